// Round 11
// baseline (469.568 us; speedup 1.0000x reference)
//
#include <hip/hip_runtime.h>
#include <stdint.h>

typedef unsigned long long u64;
typedef unsigned int u32;
typedef unsigned short u16;

#define D_      256
#define K_      1024
#define N_      131072
#define RB      64
#define MARGIN  0.024f

using short8 = __attribute__((ext_vector_type(8))) short;
using f32x4  = __attribute__((ext_vector_type(4))) float;

__device__ __forceinline__ u16 f2bf(float f) {
    u32 x = __float_as_uint(f);
    return (u16)((x + 0x7fffu + ((x >> 16) & 1u)) >> 16);
}
__device__ __forceinline__ float sqr_rn(float x) { return __fmul_rn(x, x); }
__device__ __forceinline__ float med3(float a, float b, float c) {
    return __builtin_amdgcn_fmed3f(a, b, c);
}

// numpy pairwise sum of squares over 256 elements (bitwise identical to rounds 1/3/5/6/8)
__device__ __forceinline__ float np_pairwise_sq_256(const float* p) {
    float tot[2];
#pragma unroll
    for (int blk = 0; blk < 2; ++blk) {
        const float* q = p + blk * 128;
        float r[8];
#pragma unroll
        for (int j = 0; j < 8; ++j) r[j] = sqr_rn(q[j]);
        for (int i = 8; i < 128; i += 8) {
#pragma unroll
            for (int j = 0; j < 8; ++j) r[j] = __fadd_rn(r[j], sqr_rn(q[i + j]));
        }
        tot[blk] = __fadd_rn(__fadd_rn(__fadd_rn(r[0], r[1]), __fadd_rn(r[2], r[3])),
                             __fadd_rn(__fadd_rn(r[4], r[5]), __fadd_rn(r[6], r[7])));
    }
    return __fadd_rn(tot[0], tot[1]);
}

// ------- prep (merged): E image (-2E bf16, d-major) + esq (np-pairwise) + flag_cnt=0 -------
__global__ __launch_bounds__(256)
void prep_all(const float* __restrict__ E, u16* __restrict__ EhImg,
              float* __restrict__ esq, u32* __restrict__ flag_cnt) {
    int idx  = blockIdx.x * 256 + threadIdx.x;   // 8192 tasks
    if (idx == 0) flag_cnt[0] = 0u;
    int code = idx >> 3, dc = idx & 7;
    int ct = code >> 8, lc = code & 255;
    const float4* e4 = (const float4*)(E + (size_t)code * D_ + dc * 32);
    char* tile = (char*)EhImg + ((size_t)(ct * 8 + dc) << 14);
#pragma unroll
    for (int dch = 0; dch < 4; ++dch) {
        float4 v0 = e4[dch * 2], v1 = e4[dch * 2 + 1];
        u32 a = (u32)f2bf(-2.0f * v0.x) | ((u32)f2bf(-2.0f * v0.y) << 16);
        u32 b = (u32)f2bf(-2.0f * v0.z) | ((u32)f2bf(-2.0f * v0.w) << 16);
        u32 c = (u32)f2bf(-2.0f * v1.x) | ((u32)f2bf(-2.0f * v1.y) << 16);
        u32 d = (u32)f2bf(-2.0f * v1.z) | ((u32)f2bf(-2.0f * v1.w) << 16);
        *(uint4*)(tile + (dch * 256 + lc) * 16) = make_uint4(a, b, c, d);
    }
    if (dc == 0) esq[code] = np_pairwise_sq_256(E + (size_t)code * D_);
}

// ------- prep: exact f32 transposed codebook ET[d][k] -------
__global__ __launch_bounds__(256)
void prep_et(const float* __restrict__ E, float* __restrict__ ET) {
    int t = blockIdx.x * 256 + threadIdx.x;   // 262144
    int d = t >> 10, k = t & 1023;
    ET[t] = E[(size_t)k * D_ + d];
}

// ---------------- main: top-4 tracking, __launch_bounds__(512,2) => 128-VGPR cap ----------
// (empirical: hipcc treats 2nd arg as min BLOCKS/CU: r3 (512,2)->112 VGPR, r5..r10 (512,4)
//  -> hard 64 cap -> scratch spill. 2 blocks/CU = 16 waves/CU, same occupancy as measured.)
// Outer ct (runtime) x fully-unrolled dc => bv[dc&1] STATIC. Zero barriers/atomics in
// k-loop. Per-thread sorted top-4 per row (idx in low 10 mantissa bits), one merge at end.
__global__ __launch_bounds__(512, 2)
void vq_main(const float* __restrict__ Z, const u16* __restrict__ EhImg,
             const float* __restrict__ esq_g, const float* __restrict__ E,
             u32* __restrict__ flag_cnt, u32* __restrict__ flag_list,
             u32* __restrict__ cand_g, float* __restrict__ out) {
    extern __shared__ char smem[];
    char*  zhb   = smem;                      // 32768: [64 rows][512B], byte-xor swizzle
    float* wtrip = (float*)(smem + 32768);    // [4 wc][64 row][4] = 4096
    u32*   kst   = (u32*)(smem + 36864);      // 256    (total 37120 B)

    const int t    = threadIdx.x;
    const int lane = t & 63;
    const int wv   = t >> 6;
    const int wr   = wv >> 2;
    const int wc   = wv & 3;
    const int col  = lane & 15;
    const int g    = lane >> 4;
    const int r0   = blockIdx.x * RB;
    const int asw  = (lane & 7) << 4;

    const float4* Z4 = (const float4*)(Z + (size_t)r0 * D_);
#pragma unroll
    for (int q = 0; q < 8; ++q) {
        int idx = t + 512 * q;
        int row = idx >> 6, c4 = idx & 63;
        float4 v = Z4[(size_t)row * 64 + c4];
        u32 lo = (u32)f2bf(v.x) | ((u32)f2bf(v.y) << 16);
        u32 hi = (u32)f2bf(v.z) | ((u32)f2bf(v.w) << 16);
        int boff = (c4 * 8) ^ ((row & 7) << 4);
        *(uint2*)(zhb + row * 512 + boff) = make_uint2(lo, hi);
    }
    __syncthreads();

    const char* ebase = (const char*)EhImg;
    const int   loff  = g * 4096 + wc * 1024 + col * 16;
    const u32   cbase = (u32)(wc * 64 + col);

    float trip[2][4][4];
#pragma unroll
    for (int rf = 0; rf < 2; ++rf)
#pragma unroll
        for (int i = 0; i < 4; ++i)
#pragma unroll
            for (int j = 0; j < 4; ++j) trip[rf][i][j] = 3.0e38f;

    f32x4 acc[2][4];
    short8 bv[2][4];
    {
        const char* t0 = ebase + loff;
        const char* t1 = ebase + 16384 + loff;
#pragma unroll
        for (int cf = 0; cf < 4; ++cf) {
            bv[0][cf] = *(const short8*)(t0 + cf * 256);
            bv[1][cf] = *(const short8*)(t1 + cf * 256);
        }
    }

    for (int ct = 0; ct < 4; ++ct) {
#pragma unroll
        for (int cf = 0; cf < 4; ++cf) {
            float ev = esq_g[ct * 256 + wc * 64 + cf * 16 + col];
#pragma unroll
            for (int rf = 0; rf < 2; ++rf)
                acc[rf][cf] = (f32x4){ev, ev, ev, ev};
        }
#pragma unroll
        for (int dc = 0; dc < 8; ++dc) {
            const int kb = dc * 64 + g * 16;
            short8 a[2];
#pragma unroll
            for (int rf = 0; rf < 2; ++rf) {
                int row = wr * 32 + rf * 16 + col;
                a[rf] = *(const short8*)(zhb + row * 512 + (kb ^ asw));
            }
#pragma unroll
            for (int rf = 0; rf < 2; ++rf)
#pragma unroll
                for (int cf = 0; cf < 4; ++cf)
                    acc[rf][cf] = __builtin_amdgcn_mfma_f32_16x16x32_bf16(
                        a[rf], bv[dc & 1][cf], acc[rf][cf], 0, 0, 0);
            {
                int tln = (ct * 8 + dc + 2) & 31;
                const char* tn = ebase + ((size_t)tln << 14) + loff;
#pragma unroll
                for (int cf = 0; cf < 4; ++cf)
                    bv[dc & 1][cf] = *(const short8*)(tn + cf * 256);
            }
            if (dc == 7) {
                const u32 cc0 = ((u32)ct << 8) + cbase;
#pragma unroll
                for (int rf = 0; rf < 2; ++rf)
#pragma unroll
                    for (int cf = 0; cf < 4; ++cf)
#pragma unroll
                        for (int i = 0; i < 4; ++i) {
                            u32 sb = (__float_as_uint(acc[rf][cf][i]) & 0xFFFFFC00u)
                                     | (cc0 + (u32)(cf * 16));
                            float key = __uint_as_float(sb);
                            float b0 = trip[rf][i][0], b1 = trip[rf][i][1],
                                  b2 = trip[rf][i][2], b3 = trip[rf][i][3];
                            trip[rf][i][0] = fminf(b0, key);
                            trip[rf][i][1] = med3(b0, b1, key);
                            trip[rf][i][2] = med3(b1, b2, key);
                            trip[rf][i][3] = med3(b2, b3, key);
                        }
            }
        }
    }

    // ---- in-wave bitonic merge of sorted quads across the 16 cols (proven r9) ----
#pragma unroll
    for (int st = 1; st <= 8; st <<= 1) {
#pragma unroll
        for (int rf = 0; rf < 2; ++rf)
#pragma unroll
            for (int i = 0; i < 4; ++i) {
                float a0 = trip[rf][i][0], a1 = trip[rf][i][1],
                      a2 = trip[rf][i][2], a3 = trip[rf][i][3];
                float b0 = __shfl_xor(a0, st, 64);
                float b1 = __shfl_xor(a1, st, 64);
                float b2 = __shfl_xor(a2, st, 64);
                float b3 = __shfl_xor(a3, st, 64);
                float L0 = fminf(a0, b3), L1 = fminf(a1, b2);
                float L2 = fminf(a2, b1), L3 = fminf(a3, b0);
                float M0 = fminf(L0, L2), M2 = fmaxf(L0, L2);
                float M1 = fminf(L1, L3), M3 = fmaxf(L1, L3);
                trip[rf][i][0] = fminf(M0, M1);
                trip[rf][i][1] = fmaxf(M0, M1);
                trip[rf][i][2] = fminf(M2, M3);
                trip[rf][i][3] = fmaxf(M2, M3);
            }
    }
    if (col == 0) {
#pragma unroll
        for (int rf = 0; rf < 2; ++rf)
#pragma unroll
            for (int i = 0; i < 4; ++i) {
                int row = wr * 32 + rf * 16 + g * 4 + i;
                float* wp = wtrip + (wc * 64 + row) * 4;
                wp[0] = trip[rf][i][0];
                wp[1] = trip[rf][i][1];
                wp[2] = trip[rf][i][2];
                wp[3] = trip[rf][i][3];
            }
    }
    __syncthreads();

    // ---- finalize: per row merge 4 wave-quads; winner / flag decision (proven r9) ----
    if (t < RB) {
        float v[4][4];
#pragma unroll
        for (int w = 0; w < 4; ++w) {
            const float* wp = wtrip + (w * 64 + t) * 4;
#pragma unroll
            for (int j = 0; j < 4; ++j) v[w][j] = wp[j];
        }
        float s1 = fminf(fminf(v[0][0], v[1][0]), fminf(v[2][0], v[3][0]));
        float thr = __fadd_rn(s1, MARGIN);
        bool m0 = (v[0][3] <= thr) | (v[1][3] <= thr) | (v[2][3] <= thr) | (v[3][3] <= thr);
        u32 surv[8];
        int sc = 0;
        bool ovf = false;
#pragma unroll
        for (int w = 0; w < 4; ++w)
#pragma unroll
            for (int j = 0; j < 4; ++j) {
                if (v[w][j] <= thr) {
                    if (sc < 8) surv[sc++] = __float_as_uint(v[w][j]) & 1023u;
                    else ovf = true;
                }
            }
        u32 row_g = (u32)(r0 + t);
        u32 win = __float_as_uint(s1) & 1023u;
        if (m0 | ovf) {
            u32 pos = atomicAdd(flag_cnt, 1u);
            flag_list[pos] = row_g;                          // mode 0 = full scan
        } else if (sc >= 2) {
            u32 pos = atomicAdd(flag_cnt, 1u);
            flag_list[pos] = row_g | ((u32)sc << 20);
            for (int j = 0; j < sc; ++j) cand_g[(size_t)row_g * 8 + j] = surv[j];
        }
        kst[t] = win;
    }
    __syncthreads();

    const float4* E4 = (const float4*)E;
    float4* O4 = (float4*)out;
#pragma unroll
    for (int q = 0; q < 8; ++q) {
        int idx = t + 512 * q;
        int row = idx >> 6, f4 = idx & 63;
        u32 k = kst[row] & 1023u;
        O4[(size_t)(r0 + row) * 64 + f4] = E4[(size_t)k * 64 + f4];
    }
}

// ---------------- resolve: ET coalesced full scan + 8-lane candidate dots ----------------
__device__ __forceinline__ u64 exact_key_serial(const float4* __restrict__ zr4,
                                                const float* __restrict__ E,
                                                const float* __restrict__ esq,
                                                float zs, u32 k) {
    const float4* er4 = (const float4*)(E + (size_t)k * D_);
    float c = 0.f;
#pragma unroll 8
    for (int q = 0; q < 64; ++q) {
        float4 a = zr4[q], b = er4[q];
        c = fmaf(a.x, b.x, c);
        c = fmaf(a.y, b.y, c);
        c = fmaf(a.z, b.z, c);
        c = fmaf(a.w, b.w, c);
    }
    float dist = __fadd_rn(__fsub_rn(zs, __fmul_rn(2.0f, c)), esq[k]);
    return ((u64)__float_as_uint(dist) << 32) | (u64)k;
}

__global__ __launch_bounds__(256)
void resolve_kernel(const float* __restrict__ Z, const float* __restrict__ E,
                    const float* __restrict__ esq, const u32* __restrict__ flag_cnt,
                    const u32* __restrict__ flag_list,
                    const u32* __restrict__ cand_g, const float* __restrict__ ET,
                    int use_et, float* __restrict__ out) {
    __shared__ float zbuf[4][256];
    const int lane = threadIdx.x & 63;
    const int wsl  = threadIdx.x >> 6;
    const int wid  = (blockIdx.x * 256 + threadIdx.x) >> 6;
    const int nw   = (gridDim.x * 256) >> 6;
    const u32 nf = flag_cnt[0];

    const int grp = lane >> 3, sub = lane & 7;
    const float4* E4 = (const float4*)E;
    float4* O4 = (float4*)out;

    for (u32 i = wid; i < nf; i += nw) {
        u32 e    = flag_list[i];
        u32 row  = e & 0xFFFFFu;
        u32 mode = e >> 20;
        const float* zr = Z + (size_t)row * D_;
        const float4* zr4 = (const float4*)zr;

        // np-pairwise zs, 16-lane-parallel, combine order bitwise = reference (proven r3-r10)
        float r = 0.f;
        {
            int cidx = lane & 15, blk = cidx >> 3, j = cidx & 7;
            if (lane < 16) {
                const float* q = zr + blk * 128 + j;
                r = sqr_rn(q[0]);
                for (int ii = 8; ii < 128; ii += 8) r = __fadd_rn(r, sqr_rn(q[ii]));
            }
        }
        {
            float o = __shfl_xor(r, 1, 64);  r = __fadd_rn(r, o);
            o = __shfl_xor(r, 2, 64);        r = __fadd_rn(r, o);
            o = __shfl_xor(r, 4, 64);        r = __fadd_rn(r, o);
            o = __shfl_xor(r, 8, 64);        r = __fadd_rn(r, o);
        }
        float zs = __shfl(r, 0, 64);

        u64 best = ~0ull;
        if (mode == 0u) {
            if (use_et) {
                *(float4*)&zbuf[wsl][lane * 4] = zr4[lane];
                asm volatile("s_waitcnt lgkmcnt(0)" ::: "memory");
                const float4* ET4 = (const float4*)ET;
#pragma unroll
                for (int b = 0; b < 4; ++b) {
                    int k0 = b * 256 + lane * 4;
                    float c0 = 0.f, c1 = 0.f, c2 = 0.f, c3 = 0.f;
#pragma unroll 4
                    for (int d = 0; d < 256; ++d) {
                        float zd = zbuf[wsl][d];
                        float4 ev = ET4[d * 256 + b * 64 + lane];
                        c0 = fmaf(zd, ev.x, c0);
                        c1 = fmaf(zd, ev.y, c1);
                        c2 = fmaf(zd, ev.z, c2);
                        c3 = fmaf(zd, ev.w, c3);
                    }
                    float cc[4] = {c0, c1, c2, c3};
#pragma unroll
                    for (int j = 0; j < 4; ++j) {
                        u32 k = (u32)(k0 + j);
                        float dist = __fadd_rn(__fsub_rn(zs, __fmul_rn(2.0f, cc[j])), esq[k]);
                        u64 key = ((u64)__float_as_uint(dist) << 32) | (u64)k;
                        if (key < best) best = key;
                    }
                }
            } else {
                for (u32 k = (u32)lane; k < (u32)K_; k += 64u) {
                    u64 key = exact_key_serial(zr4, E, esq, zs, k);
                    if (key < best) best = key;
                }
            }
#pragma unroll
            for (int off = 32; off >= 1; off >>= 1) {
                u64 o = __shfl_xor(best, off, 64);
                if (o < best) best = o;
            }
        } else {
            if ((u32)grp < mode) {
                u32 k = cand_g[(size_t)row * 8 + grp];
                const float4* er4 = (const float4*)(E + (size_t)k * D_);
                float c = 0.f;
#pragma unroll
                for (int q = 0; q < 8; ++q) {
                    float4 a = zr4[sub * 8 + q], b = er4[sub * 8 + q];
                    c = fmaf(a.x, b.x, c);
                    c = fmaf(a.y, b.y, c);
                    c = fmaf(a.z, b.z, c);
                    c = fmaf(a.w, b.w, c);
                }
                c = __fadd_rn(c, __shfl_xor(c, 1, 64));
                c = __fadd_rn(c, __shfl_xor(c, 2, 64));
                c = __fadd_rn(c, __shfl_xor(c, 4, 64));
                float dist = __fadd_rn(__fsub_rn(zs, __fmul_rn(2.0f, c)), esq[k]);
                best = ((u64)__float_as_uint(dist) << 32) | (u64)k;
            }
            {
                u64 o = __shfl_xor(best, 8, 64);  if (o < best) best = o;
                o = __shfl_xor(best, 16, 64);     if (o < best) best = o;
                o = __shfl_xor(best, 32, 64);     if (o < best) best = o;
            }
        }
        u32 kw = (u32)(best & 0xffffffffu);
        O4[(size_t)row * 64 + lane] = E4[(size_t)kw * 64 + lane];
    }
}

extern "C" void kernel_launch(void* const* d_in, const int* in_sizes, int n_in,
                              void* d_out, int out_size, void* d_ws, size_t ws_size,
                              hipStream_t stream) {
    const float* Z = (const float*)d_in[0];
    const float* E = (const float*)d_in[1];
    float* out = (float*)d_out;

    float* esq       = (float*)d_ws;                              // 4 KB
    u16*   EhImg     = (u16*)((char*)d_ws + 4096);                // 512 KB
    u32*   flag_cnt  = (u32*)((char*)d_ws + 528384);              // 256 B
    u32*   flag_list = (u32*)((char*)d_ws + 528640);              // 512 KB
    u32*   cand_g    = (u32*)((char*)d_ws + 1052928);             // 4 MB
    float* ET        = (float*)((char*)d_ws + 5247232);           // 1 MB (if it fits)
    int use_et = (ws_size >= (size_t)(5247232 + 1048576)) ? 1 : 0;

    prep_all<<<(K_ * 8) / 256, 256, 0, stream>>>(E, EhImg, esq, flag_cnt);
    if (use_et)
        prep_et<<<(K_ * D_) / 256, 256, 0, stream>>>(E, ET);

    const int SMEM = 37120;
    hipFuncSetAttribute((const void*)vq_main,
                        hipFuncAttributeMaxDynamicSharedMemorySize, SMEM);
    vq_main<<<N_ / RB, 512, SMEM, stream>>>(Z, EhImg, esq, E,
                                            flag_cnt, flag_list, cand_g, out);

    resolve_kernel<<<1024, 256, 0, stream>>>(Z, E, esq, flag_cnt, flag_list,
                                             cand_g, ET, use_et, out);
}

// Round 12
// 216.689 us; speedup vs baseline: 2.1670x; 2.1670x over previous
//
#include <hip/hip_runtime.h>
#include <stdint.h>

typedef unsigned long long u64;
typedef unsigned int u32;
typedef unsigned short u16;

#define D_      256
#define K_      1024
#define N_      131072
#define RB      64
#define MARGIN  0.024f
#define CAP     16

using short8 = __attribute__((ext_vector_type(8))) short;
using f32x4  = __attribute__((ext_vector_type(4))) float;

__device__ __forceinline__ u16 f2bf(float f) {
    u32 x = __float_as_uint(f);
    return (u16)((x + 0x7fffu + ((x >> 16) & 1u)) >> 16);
}
__device__ __forceinline__ float sqr_rn(float x) { return __fmul_rn(x, x); }

// async global->LDS: 16B per lane; lds base must be wave-uniform (HW adds lane*16)
#if __has_builtin(__builtin_amdgcn_global_load_lds)
__device__ __forceinline__ void gload16(const void* g_perlane, void* lds_wavebase) {
    __builtin_amdgcn_global_load_lds(
        (const __attribute__((address_space(1))) void*)g_perlane,
        (__attribute__((address_space(3))) void*)lds_wavebase, 16, 0, 0);
}
#else
__device__ __forceinline__ void gload16(const void* g_perlane, void* lds_wavebase) {
    *(uint4*)((char*)lds_wavebase + (threadIdx.x & 63) * 16) = *(const uint4*)g_perlane;
}
#endif

// numpy pairwise sum of squares over 256 elements (bitwise identical to rounds 1/3/5/6/8)
__device__ __forceinline__ float np_pairwise_sq_256(const float* p) {
    float tot[2];
#pragma unroll
    for (int blk = 0; blk < 2; ++blk) {
        const float* q = p + blk * 128;
        float r[8];
#pragma unroll
        for (int j = 0; j < 8; ++j) r[j] = sqr_rn(q[j]);
        for (int i = 8; i < 128; i += 8) {
#pragma unroll
            for (int j = 0; j < 8; ++j) r[j] = __fadd_rn(r[j], sqr_rn(q[i + j]));
        }
        tot[blk] = __fadd_rn(__fadd_rn(__fadd_rn(r[0], r[1]), __fadd_rn(r[2], r[3])),
                             __fadd_rn(__fadd_rn(r[4], r[5]), __fadd_rn(r[6], r[7])));
    }
    return __fadd_rn(tot[0], tot[1]);
}

// ------- prep (merged): E image (-2E bf16, d-major) + esq (np-pairwise) + flag_cnt=0 -------
__global__ __launch_bounds__(256)
void prep_all(const float* __restrict__ E, u16* __restrict__ EhImg,
              float* __restrict__ esq, u32* __restrict__ flag_cnt) {
    int idx  = blockIdx.x * 256 + threadIdx.x;   // 8192 tasks
    if (idx == 0) flag_cnt[0] = 0u;
    int code = idx >> 3, dc = idx & 7;
    int ct = code >> 8, lc = code & 255;
    const float4* e4 = (const float4*)(E + (size_t)code * D_ + dc * 32);
    char* tile = (char*)EhImg + ((size_t)(ct * 8 + dc) << 14);
#pragma unroll
    for (int dch = 0; dch < 4; ++dch) {
        float4 v0 = e4[dch * 2], v1 = e4[dch * 2 + 1];
        u32 a = (u32)f2bf(-2.0f * v0.x) | ((u32)f2bf(-2.0f * v0.y) << 16);
        u32 b = (u32)f2bf(-2.0f * v0.z) | ((u32)f2bf(-2.0f * v0.w) << 16);
        u32 c = (u32)f2bf(-2.0f * v1.x) | ((u32)f2bf(-2.0f * v1.y) << 16);
        u32 d = (u32)f2bf(-2.0f * v1.z) | ((u32)f2bf(-2.0f * v1.w) << 16);
        *(uint4*)(tile + (dch * 256 + lc) * 16) = make_uint4(a, b, c, d);
    }
    if (dc == 0) esq[code] = np_pairwise_sq_256(E + (size_t)code * D_);
}

// ------- prep: exact f32 transposed codebook ET[d][k] -------
__global__ __launch_bounds__(256)
void prep_et(const float* __restrict__ E, float* __restrict__ ET) {
    int t = blockIdx.x * 256 + threadIdx.x;   // 262144
    int d = t >> 10, k = t & 1023;
    ET[t] = E[(size_t)k * D_ + d];
}

// ---------------- main: r6 structure, B-path switched to global_load_lds dbuf ----------
// 64 rows x 1024 codes, 8 waves (2r x 4c). E tiles (16KB, d-major) async-staged into LDS,
// double-buffered, 1 barrier per k-step (m97 schedule). Epilogue = r6-proven per-ct append.
__global__ __launch_bounds__(512, 4)
void vq_main(const float* __restrict__ Z, const u16* __restrict__ EhImg,
             const float* __restrict__ esq_g, const float* __restrict__ E,
             u32* __restrict__ flag_cnt, u32* __restrict__ flag_list,
             u32* __restrict__ cand_g, float* __restrict__ out) {
    extern __shared__ char smem[];
    char*  zhb    = smem;                      // 32768: [64 rows][512B], byte-xor swizzle
    char*  etb0   = smem + 32768;              // 16384
    char*  etb1   = smem + 49152;              // 16384
    float* part   = (float*)(smem + 65536);    // 1024
    float* rowmin = (float*)(smem + 66560);    // 256
    u32*   cnt    = (u32*)(smem + 66816);      // 256
    float* cand_s = (float*)(smem + 67072);    // 64*16*4 = 4096
    u32*   cand_i = (u32*)(smem + 71168);      // 4096
    u32*   kst    = (u32*)(smem + 75264);      // 256   (total 75520 B -> 2 blocks/CU)

    const int t    = threadIdx.x;
    const int lane = t & 63;
    const int wv   = t >> 6;
    const int wr   = wv >> 2;        // 0..1: 32-row band
    const int wc   = wv & 3;         // 0..3: 64-code band
    const int col  = lane & 15;
    const int g    = lane >> 4;      // k-slice
    const int r0   = blockIdx.x * RB;
    const int asw  = (lane & 7) << 4;

    if (t < RB) { rowmin[t] = 3.0e38f; cnt[t] = 0u; }

    // ---- stage z tile (f32 -> bf16, row-major 512B rows, xor swizzle) ----
    const float4* Z4 = (const float4*)(Z + (size_t)r0 * D_);
#pragma unroll
    for (int q = 0; q < 8; ++q) {
        int idx = t + 512 * q;
        int row = idx >> 6, c4 = idx & 63;
        float4 v = Z4[(size_t)row * 64 + c4];
        u32 lo = (u32)f2bf(v.x) | ((u32)f2bf(v.y) << 16);
        u32 hi = (u32)f2bf(v.z) | ((u32)f2bf(v.w) << 16);
        int boff = (c4 * 8) ^ ((row & 7) << 4);
        *(uint2*)(zhb + row * 512 + boff) = make_uint2(lo, hi);
    }
    // ---- prologue: async-stage E tile 0 (wave wv covers 1KB at wv*1024, +8192) ----
    {
        const char* src = (const char*)EhImg + wv * 1024 + lane * 16;
        gload16(src, etb0 + wv * 1024);
        gload16(src + 8192, etb0 + 8192 + wv * 1024);
    }
    __syncthreads();   // drains z stores + tile-0 DMA

    const int loff = g * 4096 + wc * 1024 + col * 16;   // b-frag offset within a tile

    f32x4 acc[2][4];

    for (int ct = 0; ct < 4; ++ct) {
        // acc init: esq baked as C-in
#pragma unroll
        for (int cf = 0; cf < 4; ++cf) {
            float ev = esq_g[ct * 256 + wc * 64 + cf * 16 + col];
#pragma unroll
            for (int rf = 0; rf < 2; ++rf)
                acc[rf][cf] = (f32x4){ev, ev, ev, ev};
        }
#pragma unroll
        for (int dc = 0; dc < 8; ++dc) {
            char* cur = (dc & 1) ? etb1 : etb0;   // tl = ct*8+dc; tl&1 == dc&1 (static)
            char* nxt = (dc & 1) ? etb0 : etb1;
            // prefetch next tile (async DMA; drained by this step's barrier)
            if (dc < 7 || ct < 3) {
                int tln = ct * 8 + dc + 1;
                const char* src = (const char*)EhImg + ((size_t)tln << 14)
                                  + wv * 1024 + lane * 16;
                gload16(src, nxt + wv * 1024);
                gload16(src + 8192, nxt + 8192 + wv * 1024);
            }
            const int kb = dc * 64 + g * 16;
            short8 a[2], b[4];
#pragma unroll
            for (int rf = 0; rf < 2; ++rf) {
                int row = wr * 32 + rf * 16 + col;
                a[rf] = *(const short8*)(zhb + row * 512 + (kb ^ asw));
            }
            const char* bbase = cur + loff;
#pragma unroll
            for (int cf = 0; cf < 4; ++cf)
                b[cf] = *(const short8*)(bbase + cf * 256);
#pragma unroll
            for (int rf = 0; rf < 2; ++rf)
#pragma unroll
                for (int cf = 0; cf < 4; ++cf)
                    acc[rf][cf] = __builtin_amdgcn_mfma_f32_16x16x32_bf16(
                        a[rf], b[cf], acc[rf][cf], 0, 0, 0);
            __syncthreads();   // buffer swap safe: prefetch landed, all reads done

            if (dc == 7) {
                const int ctl = ct;
                // ---- per-ct epilogue (r6-proven): tile min -> rowmin -> append ----
#pragma unroll
                for (int rf = 0; rf < 2; ++rf)
#pragma unroll
                    for (int i = 0; i < 4; ++i) {
                        float m = fminf(fminf(acc[rf][0][i], acc[rf][1][i]),
                                        fminf(acc[rf][2][i], acc[rf][3][i]));
                        m = fminf(m, __shfl_xor(m, 1, 64));
                        m = fminf(m, __shfl_xor(m, 2, 64));
                        m = fminf(m, __shfl_xor(m, 4, 64));
                        m = fminf(m, __shfl_xor(m, 8, 64));
                        if (col == 0) part[wc * 64 + wr * 32 + rf * 16 + g * 4 + i] = m;
                    }
                __syncthreads();
                if (t < RB)
                    rowmin[t] = fminf(rowmin[t],
                        fminf(fminf(part[t], part[64 + t]),
                              fminf(part[128 + t], part[192 + t])));
                __syncthreads();
#pragma unroll
                for (int rf = 0; rf < 2; ++rf)
#pragma unroll
                    for (int i = 0; i < 4; ++i) {
                        int row = wr * 32 + rf * 16 + g * 4 + i;
                        float tv = __fadd_rn(rowmin[row], MARGIN);
#pragma unroll
                        for (int cf = 0; cf < 4; ++cf) {
                            if (acc[rf][cf][i] <= tv) {
                                u32 pos = atomicAdd(&cnt[row], 1u);
                                if (pos < (u32)CAP) {
                                    cand_s[row * CAP + pos] = acc[rf][cf][i];
                                    cand_i[row * CAP + pos] =
                                        (u32)(ctl * 256 + wc * 64 + cf * 16 + col);
                                }
                            }
                        }
                    }
                // no trailing barrier: next k-step's barrier orders appends
            }
        }
    }
    __syncthreads();   // last ct's appends complete

    // ---- final prune vs final rowmin; decide winner or flag (r6-proven) ----
    if (t < RB) {
        float tf = __fadd_rn(rowmin[t], MARGIN);
        u32 c  = cnt[t];
        u32 cc = c < (u32)CAP ? c : (u32)CAP;
        u32 surv[8];
        int sc = 0;
        for (u32 i = 0; i < cc; ++i) {
            if (cand_s[t * CAP + i] <= tf) {
                if (sc < 8) surv[sc] = cand_i[t * CAP + i];
                ++sc;
            }
        }
        u32 row_g = (u32)(r0 + t);
        u32 win = (sc > 0) ? surv[0] : 0u;
        if (c > (u32)CAP || sc > 8) {
            u32 pos = atomicAdd(flag_cnt, 1u);
            flag_list[pos] = row_g;                         // mode 0 = full scan
        } else if (sc >= 2) {
            u32 pos = atomicAdd(flag_cnt, 1u);
            flag_list[pos] = row_g | ((u32)sc << 20);
            for (int j = 0; j < sc; ++j) cand_g[(size_t)row_g * 8 + j] = surv[j];
        }
        kst[t] = win;
    }
    __syncthreads();

    // ---- gather winners (resolve overwrites flagged rows) ----
    const float4* E4 = (const float4*)E;
    float4* O4 = (float4*)out;
#pragma unroll
    for (int q = 0; q < 8; ++q) {
        int idx = t + 512 * q;
        int row = idx >> 6, f4 = idx & 63;
        u32 k = kst[row] & 1023u;
        O4[(size_t)(r0 + row) * 64 + f4] = E4[(size_t)k * 64 + f4];
    }
}

// ---------------- resolve: ET coalesced full scan + 8-lane candidate dots (r10/r11) -------
__device__ __forceinline__ u64 exact_key_serial(const float4* __restrict__ zr4,
                                                const float* __restrict__ E,
                                                const float* __restrict__ esq,
                                                float zs, u32 k) {
    const float4* er4 = (const float4*)(E + (size_t)k * D_);
    float c = 0.f;
#pragma unroll 8
    for (int q = 0; q < 64; ++q) {
        float4 a = zr4[q], b = er4[q];
        c = fmaf(a.x, b.x, c);
        c = fmaf(a.y, b.y, c);
        c = fmaf(a.z, b.z, c);
        c = fmaf(a.w, b.w, c);
    }
    float dist = __fadd_rn(__fsub_rn(zs, __fmul_rn(2.0f, c)), esq[k]);
    return ((u64)__float_as_uint(dist) << 32) | (u64)k;
}

__global__ __launch_bounds__(256)
void resolve_kernel(const float* __restrict__ Z, const float* __restrict__ E,
                    const float* __restrict__ esq, const u32* __restrict__ flag_cnt,
                    const u32* __restrict__ flag_list,
                    const u32* __restrict__ cand_g, const float* __restrict__ ET,
                    int use_et, float* __restrict__ out) {
    __shared__ float zbuf[4][256];
    const int lane = threadIdx.x & 63;
    const int wsl  = threadIdx.x >> 6;
    const int wid  = (blockIdx.x * 256 + threadIdx.x) >> 6;
    const int nw   = (gridDim.x * 256) >> 6;
    const u32 nf = flag_cnt[0];

    const int grp = lane >> 3, sub = lane & 7;
    const float4* E4 = (const float4*)E;
    float4* O4 = (float4*)out;

    for (u32 i = wid; i < nf; i += nw) {
        u32 e    = flag_list[i];
        u32 row  = e & 0xFFFFFu;
        u32 mode = e >> 20;
        const float* zr = Z + (size_t)row * D_;
        const float4* zr4 = (const float4*)zr;

        float r = 0.f;
        {
            int cidx = lane & 15, blk = cidx >> 3, j = cidx & 7;
            if (lane < 16) {
                const float* q = zr + blk * 128 + j;
                r = sqr_rn(q[0]);
                for (int ii = 8; ii < 128; ii += 8) r = __fadd_rn(r, sqr_rn(q[ii]));
            }
        }
        {
            float o = __shfl_xor(r, 1, 64);  r = __fadd_rn(r, o);
            o = __shfl_xor(r, 2, 64);        r = __fadd_rn(r, o);
            o = __shfl_xor(r, 4, 64);        r = __fadd_rn(r, o);
            o = __shfl_xor(r, 8, 64);        r = __fadd_rn(r, o);
        }
        float zs = __shfl(r, 0, 64);

        u64 best = ~0ull;
        if (mode == 0u) {
            if (use_et) {
                *(float4*)&zbuf[wsl][lane * 4] = zr4[lane];
                asm volatile("s_waitcnt lgkmcnt(0)" ::: "memory");
                const float4* ET4 = (const float4*)ET;
#pragma unroll
                for (int b = 0; b < 4; ++b) {
                    int k0 = b * 256 + lane * 4;
                    float c0 = 0.f, c1 = 0.f, c2 = 0.f, c3 = 0.f;
#pragma unroll 4
                    for (int d = 0; d < 256; ++d) {
                        float zd = zbuf[wsl][d];
                        float4 ev = ET4[d * 256 + b * 64 + lane];
                        c0 = fmaf(zd, ev.x, c0);
                        c1 = fmaf(zd, ev.y, c1);
                        c2 = fmaf(zd, ev.z, c2);
                        c3 = fmaf(zd, ev.w, c3);
                    }
                    float cc[4] = {c0, c1, c2, c3};
#pragma unroll
                    for (int j = 0; j < 4; ++j) {
                        u32 k = (u32)(k0 + j);
                        float dist = __fadd_rn(__fsub_rn(zs, __fmul_rn(2.0f, cc[j])), esq[k]);
                        u64 key = ((u64)__float_as_uint(dist) << 32) | (u64)k;
                        if (key < best) best = key;
                    }
                }
            } else {
                for (u32 k = (u32)lane; k < (u32)K_; k += 64u) {
                    u64 key = exact_key_serial(zr4, E, esq, zs, k);
                    if (key < best) best = key;
                }
            }
#pragma unroll
            for (int off = 32; off >= 1; off >>= 1) {
                u64 o = __shfl_xor(best, off, 64);
                if (o < best) best = o;
            }
        } else {
            if ((u32)grp < mode) {
                u32 k = cand_g[(size_t)row * 8 + grp];
                const float4* er4 = (const float4*)(E + (size_t)k * D_);
                float c = 0.f;
#pragma unroll
                for (int q = 0; q < 8; ++q) {
                    float4 a = zr4[sub * 8 + q], b = er4[sub * 8 + q];
                    c = fmaf(a.x, b.x, c);
                    c = fmaf(a.y, b.y, c);
                    c = fmaf(a.z, b.z, c);
                    c = fmaf(a.w, b.w, c);
                }
                c = __fadd_rn(c, __shfl_xor(c, 1, 64));
                c = __fadd_rn(c, __shfl_xor(c, 2, 64));
                c = __fadd_rn(c, __shfl_xor(c, 4, 64));
                float dist = __fadd_rn(__fsub_rn(zs, __fmul_rn(2.0f, c)), esq[k]);
                best = ((u64)__float_as_uint(dist) << 32) | (u64)k;
            }
            {
                u64 o = __shfl_xor(best, 8, 64);  if (o < best) best = o;
                o = __shfl_xor(best, 16, 64);     if (o < best) best = o;
                o = __shfl_xor(best, 32, 64);     if (o < best) best = o;
            }
        }
        u32 kw = (u32)(best & 0xffffffffu);
        O4[(size_t)row * 64 + lane] = E4[(size_t)kw * 64 + lane];
    }
}

extern "C" void kernel_launch(void* const* d_in, const int* in_sizes, int n_in,
                              void* d_out, int out_size, void* d_ws, size_t ws_size,
                              hipStream_t stream) {
    const float* Z = (const float*)d_in[0];
    const float* E = (const float*)d_in[1];
    float* out = (float*)d_out;

    float* esq       = (float*)d_ws;                              // 4 KB
    u16*   EhImg     = (u16*)((char*)d_ws + 4096);                // 512 KB
    u32*   flag_cnt  = (u32*)((char*)d_ws + 528384);              // 256 B
    u32*   flag_list = (u32*)((char*)d_ws + 528640);              // 512 KB
    u32*   cand_g    = (u32*)((char*)d_ws + 1052928);             // 4 MB
    float* ET        = (float*)((char*)d_ws + 5247232);           // 1 MB (if it fits)
    int use_et = (ws_size >= (size_t)(5247232 + 1048576)) ? 1 : 0;

    prep_all<<<(K_ * 8) / 256, 256, 0, stream>>>(E, EhImg, esq, flag_cnt);
    if (use_et)
        prep_et<<<(K_ * D_) / 256, 256, 0, stream>>>(E, ET);

    const int SMEM = 75520;
    hipFuncSetAttribute((const void*)vq_main,
                        hipFuncAttributeMaxDynamicSharedMemorySize, SMEM);
    vq_main<<<N_ / RB, 512, SMEM, stream>>>(Z, EhImg, esq, E,
                                            flag_cnt, flag_list, cand_g, out);

    resolve_kernel<<<1024, 256, 0, stream>>>(Z, E, esq, flag_cnt, flag_list,
                                             cand_g, ET, use_et, out);
}